// Round 4
// baseline (1771.589 us; speedup 1.0000x reference)
//
#include <hip/hip_runtime.h>
#include <hip/hip_fp16.h>
#include <math.h>

#define FIN 35
#define F1  64
#define BSZ 256          // nodes per coarse bucket
#define MAXNB 1024       // max buckets supported (n <= 262144)
#define CPAD 32          // ints per cursor slot: one 128B line per bucket counter

// ---------- coarse histogram: LDS-privatized, ~200K device atomics total ----------
__global__ void k_ccount(const int* __restrict__ dst, int* __restrict__ ccnt, int E, int NB) {
    __shared__ int h[MAXNB];
    for (int i = threadIdx.x; i < NB; i += blockDim.x) h[i] = 0;
    __syncthreads();
    int stride = gridDim.x * blockDim.x;
    for (int e = blockIdx.x * blockDim.x + threadIdx.x; e < E; e += stride)
        atomicAdd(&h[dst[e] >> 8], 1);
    __syncthreads();
    for (int i = threadIdx.x; i < NB; i += blockDim.x) {
        int v = h[i];
        if (v) atomicAdd(&ccnt[i * CPAD], v);
    }
}

// ---------- scan 391 bucket counts -> offsets; init padded cursors ----------
__global__ void k_scan(const int* __restrict__ ccnt, int* __restrict__ boff,
                       int* __restrict__ cursor, int NB) {
    __shared__ int s[MAXNB];
    int t = threadIdx.x;
    int v = (t < NB) ? ccnt[t * CPAD] : 0;
    s[t] = v;
    __syncthreads();
    #pragma unroll
    for (int off = 1; off < MAXNB; off <<= 1) {
        int tv = (t >= off) ? s[t - off] : 0;
        __syncthreads();
        s[t] += tv;
        __syncthreads();
    }
    if (t < NB) {
        int excl = s[t] - v;
        boff[t] = excl;
        cursor[t * CPAD] = excl;
        if (t == NB - 1) boff[NB] = s[t];
    }
}

// ---------- bucket fill: per-bucket cursor on private cachelines; stores have
// ---------- monotone addresses per bucket -> ~1x write amplification ----------
__global__ void k_fillb(const int* __restrict__ src, const int* __restrict__ dst,
                        const float* __restrict__ ew, int* __restrict__ cursor,
                        int2* __restrict__ recs, int E) {
    int e = blockIdx.x * blockDim.x + threadIdx.x;
    if (e >= E) return;
    int d = dst[e];
    int pos = atomicAdd(&cursor[(d >> 8) * CPAD], 1);
    // pack: low 24 bits = src node (n < 2^24), high 8 bits = dst-local index
    recs[pos] = make_int2(src[e] | ((d & 255) << 24), __float_as_int(ew[e]));
}

// ---------- per-bucket weighted degree in LDS -> dinv ----------
__global__ void k_deg(const int* __restrict__ boff, const int2* __restrict__ recs,
                      float* __restrict__ dinv, int n) {
    __shared__ float dsum[BSZ];
    int t = threadIdx.x, b = blockIdx.x;
    dsum[t] = 1.0f;                       // self-loop weight
    __syncthreads();
    int s0 = boff[b], s1 = boff[b + 1];
    for (int r = s0 + t; r < s1; r += BSZ) {
        int2 rec = recs[r];
        atomicAdd(&dsum[((unsigned)rec.x) >> 24], __int_as_float(rec.y));
    }
    __syncthreads();
    int node = b * BSZ + t;
    if (node < n) dinv[node] = rsqrtf(dsum[t]);
}

// ---------- layer 1 GEMM: g1[row,f] = fp16( dinv[row] * sum_k x[row,k]*W1[k,f] ) ----------
__global__ void k_gemm1(const float* __restrict__ x, const float* __restrict__ W1,
                        const float* __restrict__ dinv, __half* __restrict__ g1, int n) {
    __shared__ float W1s[FIN * F1];
    __shared__ float xs[4 * FIN];
    int tid = threadIdx.x;
    for (int i = tid; i < FIN * F1; i += 256) W1s[i] = W1[i];
    int row0 = blockIdx.x * 4;
    int nrows = min(4, n - row0);
    if (tid < nrows * FIN) xs[tid] = x[(size_t)row0 * FIN + tid];
    __syncthreads();
    int rl = tid >> 6;
    int f  = tid & 63;
    if (rl < nrows) {
        float acc = 0.0f;
        #pragma unroll
        for (int k = 0; k < FIN; k++) acc += xs[rl * FIN + k] * W1s[k * F1 + f];
        int row = row0 + rl;
        g1[(size_t)row * F1 + f] = __float2half(acc * dinv[row]);
    }
}

// ---------- layer-1 aggregation per bucket: LDS tile + LDS atomics; fused
// ---------- ReLU + layer-2 GEMM epilogue -> g2. Zero device atomics. ----------
__global__ __launch_bounds__(1024, 1) void k_agg1(
        const int* __restrict__ boff, const int2* __restrict__ recs,
        const __half* __restrict__ g1, const float* __restrict__ dinv,
        const float* __restrict__ b1, const float* __restrict__ W2,
        float* __restrict__ g2, int n) {
    __shared__ float tile[BSZ * F1];      // 64 KB, bank = lane%32 -> 2-way (free)
    int t = threadIdx.x;
    for (int i = t; i < BSZ * F1; i += 1024) tile[i] = 0.0f;
    __syncthreads();
    int b = blockIdx.x;
    int s0 = boff[b], s1 = boff[b + 1];
    int wave = t >> 6, lane = t & 63;
    // 16 waves x 4 records per iteration
    for (int r = s0 + wave * 4; r < s1; r += 64) {
        if (r + 4 <= s1) {
            int2 r0 = recs[r], r1 = recs[r + 1], r2 = recs[r + 2], r3 = recs[r + 3];
            float v0 = __half2float(g1[(size_t)(r0.x & 0xFFFFFF) * F1 + lane]);
            float v1 = __half2float(g1[(size_t)(r1.x & 0xFFFFFF) * F1 + lane]);
            float v2 = __half2float(g1[(size_t)(r2.x & 0xFFFFFF) * F1 + lane]);
            float v3 = __half2float(g1[(size_t)(r3.x & 0xFFFFFF) * F1 + lane]);
            atomicAdd(&tile[(((unsigned)r0.x) >> 24) * F1 + lane], __int_as_float(r0.y) * v0);
            atomicAdd(&tile[(((unsigned)r1.x) >> 24) * F1 + lane], __int_as_float(r1.y) * v1);
            atomicAdd(&tile[(((unsigned)r2.x) >> 24) * F1 + lane], __int_as_float(r2.y) * v2);
            atomicAdd(&tile[(((unsigned)r3.x) >> 24) * F1 + lane], __int_as_float(r3.y) * v3);
        } else {
            for (int j = 0; j < s1 - r; j++) {
                int2 rc = recs[r + j];
                float v = __half2float(g1[(size_t)(rc.x & 0xFFFFFF) * F1 + lane]);
                atomicAdd(&tile[(((unsigned)rc.x) >> 24) * F1 + lane], __int_as_float(rc.y) * v);
            }
        }
    }
    __syncthreads();
    // epilogue: wave per node (16 nodes per wave); h stays in registers
    for (int dl = wave; dl < BSZ; dl += 16) {
        int node = b * BSZ + dl;
        if (node >= n) break;
        float dv = dinv[node];
        float h = dv * (tile[dl * F1 + lane] + __half2float(g1[(size_t)node * F1 + lane])) + b1[lane];
        h = h > 0.0f ? h : 0.0f;
        float2 w2v = ((const float2*)W2)[lane];
        float z0 = h * w2v.x, z1 = h * w2v.y;
        #pragma unroll
        for (int off = 32; off > 0; off >>= 1) {
            z0 += __shfl_xor(z0, off, 64);
            z1 += __shfl_xor(z1, off, 64);
        }
        if (lane == 0) ((float2*)g2)[node] = make_float2(dv * z0, dv * z1);
    }
}

// ---------- layer-2 aggregation per bucket + bias + log_softmax ----------
__global__ void k_agg2(const int* __restrict__ boff, const int2* __restrict__ recs,
                       const float* __restrict__ g2, const float* __restrict__ dinv,
                       const float* __restrict__ b2, float* __restrict__ out, int n) {
    __shared__ float acc0[BSZ];
    __shared__ float acc1[BSZ];
    int t = threadIdx.x, b = blockIdx.x;
    acc0[t] = 0.0f; acc1[t] = 0.0f;
    __syncthreads();
    int s0 = boff[b], s1 = boff[b + 1];
    for (int r = s0 + t; r < s1; r += BSZ) {
        int2 rec = recs[r];
        float w = __int_as_float(rec.y);
        float2 gv = ((const float2*)g2)[rec.x & 0xFFFFFF];
        int dl = ((unsigned)rec.x) >> 24;
        atomicAdd(&acc0[dl], w * gv.x);
        atomicAdd(&acc1[dl], w * gv.y);
    }
    __syncthreads();
    int node = b * BSZ + t;
    if (node < n) {
        float dv = dinv[node];
        float2 sv = ((const float2*)g2)[node];       // self-loop
        float z0 = dv * (acc0[t] + sv.x) + b2[0];
        float z1 = dv * (acc1[t] + sv.y) + b2[1];
        float m = fmaxf(z0, z1);
        float lse = m + logf(expf(z0 - m) + expf(z1 - m));
        ((float2*)out)[node] = make_float2(z0 - lse, z1 - lse);
    }
}

extern "C" void kernel_launch(void* const* d_in, const int* in_sizes, int n_in,
                              void* d_out, int out_size, void* d_ws, size_t ws_size,
                              hipStream_t stream) {
    const float* x  = (const float*)d_in[0];
    const int*   ei = (const int*)d_in[1];    // [2, E]: src row then dst row
    const float* ew = (const float*)d_in[2];
    const float* W1 = (const float*)d_in[3];
    const float* b1 = (const float*)d_in[4];
    const float* W2 = (const float*)d_in[5];
    const float* b2 = (const float*)d_in[6];
    float* out = (float*)d_out;

    int n = in_sizes[0] / FIN;
    int E = in_sizes[2];
    const int* src = ei;
    const int* dst = ei + E;
    int NB = (n + BSZ - 1) / BSZ;             // 391 for n=100000 (<= MAXNB)

    // workspace carve-out, 16B-aligned
    char* ws = (char*)d_ws;
    size_t off = 0;
    auto alloc = [&](size_t bytes) -> void* {
        void* p = ws + off;
        off += (bytes + 15) & ~(size_t)15;
        return p;
    };
    int*    ccnt   = (int*)   alloc((size_t)NB * CPAD * 4);   // padded: 1 line/bucket
    int*    cursor = (int*)   alloc((size_t)NB * CPAD * 4);
    int*    boff   = (int*)   alloc((size_t)(NB + 1) * 4);
    float*  dinv   = (float*) alloc((size_t)n * 4);
    int2*   recs   = (int2*)  alloc((size_t)E * 8);           // 25.6 MB
    __half* g1     = (__half*)alloc((size_t)n * F1 * 2);      // 12.8 MB
    float*  g2     = (float*) alloc((size_t)n * 2 * 4);

    hipMemsetAsync(ccnt, 0, (size_t)NB * CPAD * 4, stream);

    k_ccount<<<512, 256, 0, stream>>>(dst, ccnt, E, NB);
    k_scan  <<<1, MAXNB, 0, stream>>>(ccnt, boff, cursor, NB);
    k_fillb <<<(E + 255) / 256, 256, 0, stream>>>(src, dst, ew, cursor, recs, E);
    k_deg   <<<NB, BSZ, 0, stream>>>(boff, recs, dinv, n);
    k_gemm1 <<<(n + 3) / 4, 256, 0, stream>>>(x, W1, dinv, g1, n);
    k_agg1  <<<NB, 1024, 0, stream>>>(boff, recs, g1, dinv, b1, W2, g2, n);
    k_agg2  <<<NB, BSZ, 0, stream>>>(boff, recs, g2, dinv, b2, out, n);
}

// Round 5
// 518.112 us; speedup vs baseline: 3.4193x; 3.4193x over previous
//
#include <hip/hip_runtime.h>
#include <hip/hip_fp16.h>
#include <math.h>

#define FIN 35
#define F1  64
#define BSZ 256          // nodes per coarse bucket
#define MAXNB 1024       // max buckets supported (n <= 262144)
#define CPAD 32          // ints per cursor slot: one 128B line per bucket counter

// ---------- coarse histogram: LDS-privatized; ~NB*gridDim device atomics ----------
__global__ void k_ccount(const int* __restrict__ dst, int* __restrict__ ccnt, int E, int NB) {
    __shared__ int h[MAXNB];
    for (int i = threadIdx.x; i < NB; i += blockDim.x) h[i] = 0;
    __syncthreads();
    int stride = gridDim.x * blockDim.x;
    for (int e = blockIdx.x * blockDim.x + threadIdx.x; e < E; e += stride)
        atomicAdd(&h[dst[e] >> 8], 1);
    __syncthreads();
    for (int i = threadIdx.x; i < NB; i += blockDim.x) {
        int v = h[i];
        if (v) atomicAdd(&ccnt[i * CPAD], v);
    }
}

// ---------- scan bucket counts -> offsets; init padded cursors ----------
__global__ void k_scan(const int* __restrict__ ccnt, int* __restrict__ boff,
                       int* __restrict__ cursor, int NB) {
    __shared__ int s[MAXNB];
    int t = threadIdx.x;
    int v = (t < NB) ? ccnt[t * CPAD] : 0;
    s[t] = v;
    __syncthreads();
    #pragma unroll
    for (int off = 1; off < MAXNB; off <<= 1) {
        int tv = (t >= off) ? s[t - off] : 0;
        __syncthreads();
        s[t] += tv;
        __syncthreads();
    }
    if (t < NB) {
        int excl = s[t] - v;
        boff[t] = excl;
        cursor[t * CPAD] = excl;
        if (t == NB - 1) boff[NB] = s[t];
    }
}

// ---------- bucket fill: per-bucket cursors on private cachelines; store working
// ---------- set = NB tail lines (L2-resident) -> ~1x write amplification ----------
__global__ void k_fillb(const int* __restrict__ src, const int* __restrict__ dst,
                        const float* __restrict__ ew, int* __restrict__ cursor,
                        int2* __restrict__ recs, int E) {
    int e = blockIdx.x * blockDim.x + threadIdx.x;
    if (e >= E) return;
    int d = dst[e];
    int pos = atomicAdd(&cursor[(d >> 8) * CPAD], 1);
    // pack: low 24 bits = src node (n < 2^24), high 8 bits = dst-local index
    recs[pos] = make_int2(src[e] | ((d & 255) << 24), __float_as_int(ew[e]));
}

// ---------- per-bucket counting sort (LDS) -> per-node CSR; also row_ptr + dinv ----------
__global__ void k_sort(const int* __restrict__ boff, const int2* __restrict__ recs_in,
                       int2* __restrict__ recs_out, int* __restrict__ row_ptr,
                       float* __restrict__ dinv, int n, int NB) {
    __shared__ int   hcnt[BSZ];   // per-local-node count, then cursor
    __shared__ int   hoff[BSZ];   // scan scratch
    __shared__ float dsum[BSZ];   // weighted degree
    int b = blockIdx.x, t = threadIdx.x;
    hcnt[t] = 0;
    dsum[t] = 1.0f;               // self-loop weight
    __syncthreads();
    int s0 = boff[b], s1 = boff[b + 1];
    // pass 1: histogram + weighted degree
    for (int r = s0 + t; r < s1; r += BSZ) {
        int2 rec = recs_in[r];
        int dl = ((unsigned)rec.x) >> 24;
        atomicAdd(&hcnt[dl], 1);
        atomicAdd(&dsum[dl], __int_as_float(rec.y));
    }
    __syncthreads();
    int v = hcnt[t];
    hoff[t] = v;
    __syncthreads();
    #pragma unroll
    for (int off = 1; off < BSZ; off <<= 1) {
        int tv = (t >= off) ? hoff[t - off] : 0;
        __syncthreads();
        hoff[t] += tv;
        __syncthreads();
    }
    int excl = hoff[t] - v;       // local exclusive prefix
    int node = b * BSZ + t;
    if (node < n) {
        row_ptr[node] = s0 + excl;
        dinv[node] = rsqrtf(dsum[t]);
        if (node == n - 1) row_ptr[n] = s1;
    }
    __syncthreads();
    hcnt[t] = excl;               // reuse as local cursor
    __syncthreads();
    // pass 2: scatter within this bucket's 65KB slice (L2-resident writes)
    for (int r = s0 + t; r < s1; r += BSZ) {
        int2 rec = recs_in[r];
        int dl = ((unsigned)rec.x) >> 24;
        int pos = atomicAdd(&hcnt[dl], 1);
        recs_out[s0 + pos] = make_int2(rec.x & 0xFFFFFF, rec.y);  // clean src
    }
}

// ---------- layer 1 GEMM: g1[row,f] = fp16( dinv[row] * sum_k x[row,k]*W1[k,f] ) ----------
__global__ void k_gemm1(const float* __restrict__ x, const float* __restrict__ W1,
                        const float* __restrict__ dinv, __half* __restrict__ g1, int n) {
    __shared__ float W1s[FIN * F1];
    __shared__ float xs[4 * FIN];
    int tid = threadIdx.x;
    for (int i = tid; i < FIN * F1; i += 256) W1s[i] = W1[i];
    int row0 = blockIdx.x * 4;
    int nrows = min(4, n - row0);
    if (tid < nrows * FIN) xs[tid] = x[(size_t)row0 * FIN + tid];
    __syncthreads();
    int rl = tid >> 6;
    int f  = tid & 63;
    if (rl < nrows) {
        float acc = 0.0f;
        #pragma unroll
        for (int k = 0; k < FIN; k++) acc += xs[rl * FIN + k] * W1s[k * F1 + f];
        int row = row0 + rl;
        g1[(size_t)row * F1 + f] = __float2half(acc * dinv[row]);
    }
}

// ---------- fused: layer-1 gather (fp16 rows) + ReLU + layer-2 GEMM (64->2) ----------
// one wave per node; lane = feature; 100K waves of TLP to hide gather latency.
__global__ void k_gather1(const int* __restrict__ rp, const int2* __restrict__ csr,
                          const __half* __restrict__ g1,
                          const float* __restrict__ dinv, const float* __restrict__ b1,
                          const float* __restrict__ W2, float* __restrict__ g2, int n) {
    int wid = (int)((blockIdx.x * (long long)blockDim.x + threadIdx.x) >> 6);
    int f = threadIdx.x & 63;
    if (wid >= n) return;
    int start = rp[wid], end = rp[wid + 1];
    float acc = 0.0f;
    int e = start;
    for (; e + 4 <= end; e += 4) {             // 4-way ILP on the gather loads
        int2 r0 = csr[e], r1 = csr[e+1], r2 = csr[e+2], r3 = csr[e+3];
        float a0 = __half2float(g1[(size_t)r0.x * F1 + f]);
        float a1 = __half2float(g1[(size_t)r1.x * F1 + f]);
        float a2 = __half2float(g1[(size_t)r2.x * F1 + f]);
        float a3 = __half2float(g1[(size_t)r3.x * F1 + f]);
        acc += __int_as_float(r0.y) * a0;
        acc += __int_as_float(r1.y) * a1;
        acc += __int_as_float(r2.y) * a2;
        acc += __int_as_float(r3.y) * a3;
    }
    for (; e < end; e++) {
        int2 r = csr[e];
        acc += __int_as_float(r.y) * __half2float(g1[(size_t)r.x * F1 + f]);
    }
    float dv = dinv[wid];
    float h = dv * (acc + __half2float(g1[(size_t)wid * F1 + f])) + b1[f]; // self-loop w=1
    h = h > 0.0f ? h : 0.0f;
    float2 w2v = ((const float2*)W2)[f];
    float z0 = h * w2v.x, z1 = h * w2v.y;
    #pragma unroll
    for (int off = 32; off > 0; off >>= 1) {
        z0 += __shfl_xor(z0, off, 64);
        z1 += __shfl_xor(z1, off, 64);
    }
    if (f == 0) {
        g2[(size_t)wid * 2 + 0] = dv * z0;
        g2[(size_t)wid * 2 + 1] = dv * z1;
    }
}

// ---------- fused: layer-2 gather + bias + log_softmax ----------
__global__ void k_gather2(const int* __restrict__ rp, const int2* __restrict__ csr,
                          const float* __restrict__ g2,
                          const float* __restrict__ dinv, const float* __restrict__ b2,
                          float* __restrict__ out, int n) {
    int wid = (int)((blockIdx.x * (long long)blockDim.x + threadIdx.x) >> 6);
    int lane = threadIdx.x & 63;
    if (wid >= n) return;
    int start = rp[wid], end = rp[wid + 1];
    float a0 = 0.0f, a1 = 0.0f;
    for (int e = start + lane; e < end; e += 64) {   // coalesced csr reads
        int2 r = csr[e];
        float w = __int_as_float(r.y);
        float2 gv = ((const float2*)g2)[r.x];
        a0 += w * gv.x; a1 += w * gv.y;
    }
    #pragma unroll
    for (int off = 32; off > 0; off >>= 1) {
        a0 += __shfl_xor(a0, off, 64);
        a1 += __shfl_xor(a1, off, 64);
    }
    if (lane == 0) {
        float dv = dinv[wid];
        float2 sv = ((const float2*)g2)[wid];        // self-loop
        float z0 = dv * (a0 + sv.x) + b2[0];
        float z1 = dv * (a1 + sv.y) + b2[1];
        float m = fmaxf(z0, z1);
        float lse = m + logf(expf(z0 - m) + expf(z1 - m));
        ((float2*)out)[wid] = make_float2(z0 - lse, z1 - lse);
    }
}

extern "C" void kernel_launch(void* const* d_in, const int* in_sizes, int n_in,
                              void* d_out, int out_size, void* d_ws, size_t ws_size,
                              hipStream_t stream) {
    const float* x  = (const float*)d_in[0];
    const int*   ei = (const int*)d_in[1];    // [2, E]: src row then dst row
    const float* ew = (const float*)d_in[2];
    const float* W1 = (const float*)d_in[3];
    const float* b1 = (const float*)d_in[4];
    const float* W2 = (const float*)d_in[5];
    const float* b2 = (const float*)d_in[6];
    float* out = (float*)d_out;

    int n = in_sizes[0] / FIN;
    int E = in_sizes[2];
    const int* src = ei;
    const int* dst = ei + E;
    int NB = (n + BSZ - 1) / BSZ;             // 391 for n=100000 (<= MAXNB)

    // workspace carve-out, 16B-aligned
    char* ws = (char*)d_ws;
    size_t off = 0;
    auto alloc = [&](size_t bytes) -> void* {
        void* p = ws + off;
        off += (bytes + 15) & ~(size_t)15;
        return p;
    };
    int*    ccnt    = (int*)   alloc((size_t)NB * CPAD * 4);
    int*    cursor  = (int*)   alloc((size_t)NB * CPAD * 4);
    int*    boff    = (int*)   alloc((size_t)(NB + 1) * 4);
    int*    row_ptr = (int*)   alloc((size_t)(n + 1) * 4);
    float*  dinv    = (float*) alloc((size_t)n * 4);
    int2*   recs_a  = (int2*)  alloc((size_t)E * 8);      // 25.6 MB (bucket order)
    int2*   recs_b  = (int2*)  alloc((size_t)E * 8);      // 25.6 MB (node order)
    __half* g1      = (__half*)alloc((size_t)n * F1 * 2); // 12.8 MB
    float*  g2      = (float*) alloc((size_t)n * 2 * 4);

    hipMemsetAsync(ccnt, 0, (size_t)NB * CPAD * 4, stream);

    k_ccount <<<1024, 256, 0, stream>>>(dst, ccnt, E, NB);
    k_scan   <<<1, MAXNB, 0, stream>>>(ccnt, boff, cursor, NB);
    k_fillb  <<<(E + 255) / 256, 256, 0, stream>>>(src, dst, ew, cursor, recs_a, E);
    k_sort   <<<NB, BSZ, 0, stream>>>(boff, recs_a, recs_b, row_ptr, dinv, n, NB);
    k_gemm1  <<<(n + 3) / 4, 256, 0, stream>>>(x, W1, dinv, g1, n);
    k_gather1<<<(n + 3) / 4, 256, 0, stream>>>(row_ptr, recs_b, g1, dinv, b1, W2, g2, n);
    k_gather2<<<(n + 3) / 4, 256, 0, stream>>>(row_ptr, recs_b, g2, dinv, b2, out, n);
}

// Round 6
// 517.921 us; speedup vs baseline: 3.4206x; 1.0004x over previous
//
#include <hip/hip_runtime.h>
#include <hip/hip_fp16.h>
#include <math.h>

#define FIN 35
#define F1  64
#define BSZ 256          // nodes per coarse bucket
#define MAXNB 1024       // max buckets supported (n <= 262144)
#define CHUNK 16384      // edges per partition block (64 per thread)

// ---------- phase 1: per-chunk histogram of coarse buckets ----------
__global__ void k_hist(const int* __restrict__ dst, int* __restrict__ cmat,
                       int E, int NB, int NCHUNK) {
    __shared__ int h[MAXNB];
    int c = blockIdx.x, t = threadIdx.x;
    for (int i = t; i < NB; i += 256) h[i] = 0;
    __syncthreads();
    int e0 = c * CHUNK, e1 = min(e0 + CHUNK, E);
    for (int e = e0 + t; e < e1; e += 256) atomicAdd(&h[dst[e] >> 8], 1);
    __syncthreads();
    for (int i = t; i < NB; i += 256) cmat[(size_t)i * NCHUNK + c] = h[i];  // b-major
}

// ---------- phase 2: exclusive scan of cmat (b-major) -> exact placement offsets ----------
__global__ void k_scanM(int* __restrict__ cmat, int* __restrict__ boff,
                        int M, int NB, int NCHUNK, int E) {
    __shared__ int tsum[1024];
    int t = threadIdx.x;
    int per = (M + 1023) / 1024;
    int i0 = t * per, i1 = min(i0 + per, M);
    int s = 0;
    for (int i = i0; i < i1; i++) s += cmat[i];
    tsum[t] = s;
    __syncthreads();
    #pragma unroll
    for (int off = 1; off < 1024; off <<= 1) {
        int v = (t >= off) ? tsum[t - off] : 0;
        __syncthreads();
        tsum[t] += v;
        __syncthreads();
    }
    int run = (t > 0) ? tsum[t - 1] : 0;
    for (int i = i0; i < i1; i++) {
        int v = cmat[i];
        cmat[i] = run;          // exclusive prefix
        run += v;
    }
    __syncthreads();            // workgroup barrier orders the global writes above
    for (int b = t; b < NB; b += 1024) boff[b] = cmat[(size_t)b * NCHUNK];
    if (t == 0) boff[NB] = E;
}

// ---------- phase 3: placement — disjoint per-(block,bucket) windows, zero device atomics ----------
__global__ void k_place(const int* __restrict__ src, const int* __restrict__ dst,
                        const float* __restrict__ ew, const int* __restrict__ cmat,
                        int2* __restrict__ recs, int E, int NB, int NCHUNK) {
    __shared__ int base[MAXNB];
    __shared__ int cur[MAXNB];
    int c = blockIdx.x, t = threadIdx.x;
    for (int i = t; i < NB; i += 256) { base[i] = cmat[(size_t)i * NCHUNK + c]; cur[i] = 0; }
    __syncthreads();
    int e0 = c * CHUNK, e1 = min(e0 + CHUNK, E);
    for (int e = e0 + t; e < e1; e += 256) {
        int d = dst[e];
        int b = d >> 8;
        int r = atomicAdd(&cur[b], 1);          // LDS atomic only
        // pack: low 24 bits = src node (n < 2^24), high 8 bits = dst-local index
        recs[base[b] + r] = make_int2(src[e] | ((d & 255) << 24), __float_as_int(ew[e]));
    }
}

// ---------- per-bucket counting sort (LDS) -> per-node CSR; also row_ptr + dinv ----------
__global__ void k_sort(const int* __restrict__ boff, const int2* __restrict__ recs_in,
                       int2* __restrict__ recs_out, int* __restrict__ row_ptr,
                       float* __restrict__ dinv, int n) {
    __shared__ int   hcnt[BSZ];   // per-local-node count, then cursor
    __shared__ int   hoff[BSZ];   // scan scratch
    __shared__ float dsum[BSZ];   // weighted degree
    int b = blockIdx.x, t = threadIdx.x;
    hcnt[t] = 0;
    dsum[t] = 1.0f;               // self-loop weight
    __syncthreads();
    int s0 = boff[b], s1 = boff[b + 1];
    for (int r = s0 + t; r < s1; r += BSZ) {
        int2 rec = recs_in[r];
        int dl = ((unsigned)rec.x) >> 24;
        atomicAdd(&hcnt[dl], 1);
        atomicAdd(&dsum[dl], __int_as_float(rec.y));
    }
    __syncthreads();
    int v = hcnt[t];
    hoff[t] = v;
    __syncthreads();
    #pragma unroll
    for (int off = 1; off < BSZ; off <<= 1) {
        int tv = (t >= off) ? hoff[t - off] : 0;
        __syncthreads();
        hoff[t] += tv;
        __syncthreads();
    }
    int excl = hoff[t] - v;
    int node = b * BSZ + t;
    if (node < n) {
        row_ptr[node] = s0 + excl;
        dinv[node] = rsqrtf(dsum[t]);
        if (node == n - 1) row_ptr[n] = s1;
    }
    __syncthreads();
    hcnt[t] = excl;               // reuse as local cursor
    __syncthreads();
    for (int r = s0 + t; r < s1; r += BSZ) {
        int2 rec = recs_in[r];
        int dl = ((unsigned)rec.x) >> 24;
        int pos = atomicAdd(&hcnt[dl], 1);
        recs_out[s0 + pos] = make_int2(rec.x & 0xFFFFFF, rec.y);  // clean src
    }
}

// ---------- layer 1 GEMM: g1[row,f] = fp16( dinv[row] * sum_k x[row,k]*W1[k,f] ) ----------
__global__ void k_gemm1(const float* __restrict__ x, const float* __restrict__ W1,
                        const float* __restrict__ dinv, __half* __restrict__ g1, int n) {
    __shared__ float W1s[FIN * F1];
    __shared__ float xs[4 * FIN];
    int tid = threadIdx.x;
    for (int i = tid; i < FIN * F1; i += 256) W1s[i] = W1[i];
    int row0 = blockIdx.x * 4;
    int nrows = min(4, n - row0);
    if (tid < nrows * FIN) xs[tid] = x[(size_t)row0 * FIN + tid];
    __syncthreads();
    int rl = tid >> 6;
    int f  = tid & 63;
    if (rl < nrows) {
        float acc = 0.0f;
        #pragma unroll
        for (int k = 0; k < FIN; k++) acc += xs[rl * FIN + k] * W1s[k * F1 + f];
        int row = row0 + rl;
        g1[(size_t)row * F1 + f] = __float2half(acc * dinv[row]);
    }
}

// ---------- fused: layer-1 gather (fp16 rows) + ReLU + layer-2 GEMM (64->2) ----------
__global__ void k_gather1(const int* __restrict__ rp, const int2* __restrict__ csr,
                          const __half* __restrict__ g1,
                          const float* __restrict__ dinv, const float* __restrict__ b1,
                          const float* __restrict__ W2, float* __restrict__ g2, int n) {
    int wid = (int)((blockIdx.x * (long long)blockDim.x + threadIdx.x) >> 6);
    int f = threadIdx.x & 63;
    if (wid >= n) return;
    int start = rp[wid], end = rp[wid + 1];
    float acc = 0.0f;
    int e = start;
    for (; e + 4 <= end; e += 4) {
        int2 r0 = csr[e], r1 = csr[e+1], r2 = csr[e+2], r3 = csr[e+3];
        float a0 = __half2float(g1[(size_t)r0.x * F1 + f]);
        float a1 = __half2float(g1[(size_t)r1.x * F1 + f]);
        float a2 = __half2float(g1[(size_t)r2.x * F1 + f]);
        float a3 = __half2float(g1[(size_t)r3.x * F1 + f]);
        acc += __int_as_float(r0.y) * a0;
        acc += __int_as_float(r1.y) * a1;
        acc += __int_as_float(r2.y) * a2;
        acc += __int_as_float(r3.y) * a3;
    }
    for (; e < end; e++) {
        int2 r = csr[e];
        acc += __int_as_float(r.y) * __half2float(g1[(size_t)r.x * F1 + f]);
    }
    float dv = dinv[wid];
    float h = dv * (acc + __half2float(g1[(size_t)wid * F1 + f])) + b1[f]; // self-loop w=1
    h = h > 0.0f ? h : 0.0f;
    float2 w2v = ((const float2*)W2)[f];
    float z0 = h * w2v.x, z1 = h * w2v.y;
    #pragma unroll
    for (int off = 32; off > 0; off >>= 1) {
        z0 += __shfl_xor(z0, off, 64);
        z1 += __shfl_xor(z1, off, 64);
    }
    if (f == 0) {
        g2[(size_t)wid * 2 + 0] = dv * z0;
        g2[(size_t)wid * 2 + 1] = dv * z1;
    }
}

// ---------- fused: layer-2 gather + bias + log_softmax ----------
__global__ void k_gather2(const int* __restrict__ rp, const int2* __restrict__ csr,
                          const float* __restrict__ g2,
                          const float* __restrict__ dinv, const float* __restrict__ b2,
                          float* __restrict__ out, int n) {
    int wid = (int)((blockIdx.x * (long long)blockDim.x + threadIdx.x) >> 6);
    int lane = threadIdx.x & 63;
    if (wid >= n) return;
    int start = rp[wid], end = rp[wid + 1];
    float a0 = 0.0f, a1 = 0.0f;
    for (int e = start + lane; e < end; e += 64) {
        int2 r = csr[e];
        float w = __int_as_float(r.y);
        float2 gv = ((const float2*)g2)[r.x];
        a0 += w * gv.x; a1 += w * gv.y;
    }
    #pragma unroll
    for (int off = 32; off > 0; off >>= 1) {
        a0 += __shfl_xor(a0, off, 64);
        a1 += __shfl_xor(a1, off, 64);
    }
    if (lane == 0) {
        float dv = dinv[wid];
        float2 sv = ((const float2*)g2)[wid];        // self-loop
        float z0 = dv * (a0 + sv.x) + b2[0];
        float z1 = dv * (a1 + sv.y) + b2[1];
        float m = fmaxf(z0, z1);
        float lse = m + logf(expf(z0 - m) + expf(z1 - m));
        ((float2*)out)[wid] = make_float2(z0 - lse, z1 - lse);
    }
}

extern "C" void kernel_launch(void* const* d_in, const int* in_sizes, int n_in,
                              void* d_out, int out_size, void* d_ws, size_t ws_size,
                              hipStream_t stream) {
    const float* x  = (const float*)d_in[0];
    const int*   ei = (const int*)d_in[1];    // [2, E]: src row then dst row
    const float* ew = (const float*)d_in[2];
    const float* W1 = (const float*)d_in[3];
    const float* b1 = (const float*)d_in[4];
    const float* W2 = (const float*)d_in[5];
    const float* b2 = (const float*)d_in[6];
    float* out = (float*)d_out;

    int n = in_sizes[0] / FIN;
    int E = in_sizes[2];
    const int* src = ei;
    const int* dst = ei + E;
    int NB = (n + BSZ - 1) / BSZ;             // 391 for n=100000 (<= MAXNB)
    int NCHUNK = (E + CHUNK - 1) / CHUNK;     // 196 for E=3.2M
    int M = NB * NCHUNK;

    // workspace carve-out, 16B-aligned
    char* ws = (char*)d_ws;
    size_t off = 0;
    auto alloc = [&](size_t bytes) -> void* {
        void* p = ws + off;
        off += (bytes + 15) & ~(size_t)15;
        return p;
    };
    int*    cmat    = (int*)   alloc((size_t)M * 4);      // 306 KB placement matrix
    int*    boff    = (int*)   alloc((size_t)(NB + 1) * 4);
    int*    row_ptr = (int*)   alloc((size_t)(n + 1) * 4);
    float*  dinv    = (float*) alloc((size_t)n * 4);
    int2*   recs_a  = (int2*)  alloc((size_t)E * 8);      // 25.6 MB (bucket order)
    int2*   recs_b  = (int2*)  alloc((size_t)E * 8);      // 25.6 MB (node order)
    __half* g1      = (__half*)alloc((size_t)n * F1 * 2); // 12.8 MB
    float*  g2      = (float*) alloc((size_t)n * 2 * 4);

    k_hist   <<<NCHUNK, 256, 0, stream>>>(dst, cmat, E, NB, NCHUNK);
    k_scanM  <<<1, 1024, 0, stream>>>(cmat, boff, M, NB, NCHUNK, E);
    k_place  <<<NCHUNK, 256, 0, stream>>>(src, dst, ew, cmat, recs_a, E, NB, NCHUNK);
    k_sort   <<<NB, BSZ, 0, stream>>>(boff, recs_a, recs_b, row_ptr, dinv, n);
    k_gemm1  <<<(n + 3) / 4, 256, 0, stream>>>(x, W1, dinv, g1, n);
    k_gather1<<<(n + 3) / 4, 256, 0, stream>>>(row_ptr, recs_b, g1, dinv, b1, W2, g2, n);
    k_gather2<<<(n + 3) / 4, 256, 0, stream>>>(row_ptr, recs_b, g2, dinv, b2, out, n);
}

// Round 7
// 409.770 us; speedup vs baseline: 4.3234x; 1.2639x over previous
//
#include <hip/hip_runtime.h>
#include <hip/hip_fp16.h>
#include <math.h>

#define FIN 35
#define F1  64
#define BSZ 256          // nodes per coarse bucket
#define MAXNB 1024       // max buckets supported by k_hist/k_place LDS (n <= 262144)
#define CHUNK 16384      // edges per partition block => NCHUNK <= 256 for E <= 4.19M

// ---------- phase 1: per-chunk histogram of coarse buckets ----------
__global__ void k_hist(const int* __restrict__ dst, int* __restrict__ cmat,
                       int E, int NB, int NCHUNK) {
    __shared__ int h[MAXNB];
    int c = blockIdx.x, t = threadIdx.x;
    for (int i = t; i < NB; i += 256) h[i] = 0;
    __syncthreads();
    int e0 = c * CHUNK, e1 = min(e0 + CHUNK, E);
    for (int e = e0 + t; e < e1; e += 256) atomicAdd(&h[dst[e] >> 8], 1);
    __syncthreads();
    for (int i = t; i < NB; i += 256) cmat[(size_t)i * NCHUNK + c] = h[i];  // b-major
}

// ---------- phase 2a: row-local exclusive scan (one block per bucket row) ----------
// requires NCHUNK <= 256
__global__ void k_scan_row(int* __restrict__ cmat, int* __restrict__ rsum, int NCHUNK) {
    __shared__ int s[256];
    int b = blockIdx.x, t = threadIdx.x;
    int v = (t < NCHUNK) ? cmat[(size_t)b * NCHUNK + t] : 0;
    s[t] = v;
    __syncthreads();
    #pragma unroll
    for (int off = 1; off < 256; off <<= 1) {
        int tv = (t >= off) ? s[t - off] : 0;
        __syncthreads();
        s[t] += tv;
        __syncthreads();
    }
    if (t < NCHUNK) cmat[(size_t)b * NCHUNK + t] = s[t] - v;   // row-local exclusive
    if (t == 255) rsum[b] = s[255];                            // row total
}

// ---------- phase 2b: exclusive scan of row totals -> bucket bases + boff ----------
// requires NB <= 512
__global__ void k_scan_buck(const int* __restrict__ rsum, int* __restrict__ bbase,
                            int* __restrict__ boff, int NB, int E) {
    __shared__ int s[512];
    int t = threadIdx.x;
    int v = (t < NB) ? rsum[t] : 0;
    s[t] = v;
    __syncthreads();
    #pragma unroll
    for (int off = 1; off < 512; off <<= 1) {
        int tv = (t >= off) ? s[t - off] : 0;
        __syncthreads();
        s[t] += tv;
        __syncthreads();
    }
    if (t < NB) {
        int excl = s[t] - v;
        bbase[t] = excl;
        boff[t] = excl;
    }
    if (t == 0) boff[NB] = E;
}

// ---------- phase 3: placement — disjoint per-(block,bucket) windows, zero device atomics ----------
__global__ void k_place(const int* __restrict__ src, const int* __restrict__ dst,
                        const float* __restrict__ ew, const int* __restrict__ cmat,
                        const int* __restrict__ bbase,
                        int2* __restrict__ recs, int E, int NB, int NCHUNK) {
    __shared__ int base[MAXNB];
    __shared__ int cur[MAXNB];
    int c = blockIdx.x, t = threadIdx.x;
    for (int i = t; i < NB; i += 256) {
        base[i] = cmat[(size_t)i * NCHUNK + c] + bbase[i];   // fused "+bucket base"
        cur[i] = 0;
    }
    __syncthreads();
    int e0 = c * CHUNK, e1 = min(e0 + CHUNK, E);
    for (int e = e0 + t; e < e1; e += 256) {
        int d = dst[e];
        int b = d >> 8;
        int r = atomicAdd(&cur[b], 1);          // LDS atomic only
        // pack: low 24 bits = src node (n < 2^24), high 8 bits = dst-local index
        recs[base[b] + r] = make_int2(src[e] | ((d & 255) << 24), __float_as_int(ew[e]));
    }
}

// ---------- per-bucket counting sort (LDS) -> per-node CSR; also row_ptr + dinv ----------
__global__ void k_sort(const int* __restrict__ boff, const int2* __restrict__ recs_in,
                       int2* __restrict__ recs_out, int* __restrict__ row_ptr,
                       float* __restrict__ dinv, int n) {
    __shared__ int   hcnt[BSZ];   // per-local-node count, then cursor
    __shared__ int   hoff[BSZ];   // scan scratch
    __shared__ float dsum[BSZ];   // weighted degree
    int b = blockIdx.x, t = threadIdx.x;
    hcnt[t] = 0;
    dsum[t] = 1.0f;               // self-loop weight
    __syncthreads();
    int s0 = boff[b], s1 = boff[b + 1];
    for (int r = s0 + t; r < s1; r += BSZ) {
        int2 rec = recs_in[r];
        int dl = ((unsigned)rec.x) >> 24;
        atomicAdd(&hcnt[dl], 1);
        atomicAdd(&dsum[dl], __int_as_float(rec.y));
    }
    __syncthreads();
    int v = hcnt[t];
    hoff[t] = v;
    __syncthreads();
    #pragma unroll
    for (int off = 1; off < BSZ; off <<= 1) {
        int tv = (t >= off) ? hoff[t - off] : 0;
        __syncthreads();
        hoff[t] += tv;
        __syncthreads();
    }
    int excl = hoff[t] - v;
    int node = b * BSZ + t;
    if (node < n) {
        row_ptr[node] = s0 + excl;
        dinv[node] = rsqrtf(dsum[t]);
        if (node == n - 1) row_ptr[n] = s1;
    }
    __syncthreads();
    hcnt[t] = excl;               // reuse as local cursor
    __syncthreads();
    for (int r = s0 + t; r < s1; r += BSZ) {
        int2 rec = recs_in[r];
        int dl = ((unsigned)rec.x) >> 24;
        int pos = atomicAdd(&hcnt[dl], 1);
        recs_out[s0 + pos] = make_int2(rec.x & 0xFFFFFF, rec.y);  // clean src
    }
}

// ---------- layer 1 GEMM: g1[row,f] = fp16( dinv[row] * sum_k x[row,k]*W1[k,f] ) ----------
__global__ void k_gemm1(const float* __restrict__ x, const float* __restrict__ W1,
                        const float* __restrict__ dinv, __half* __restrict__ g1, int n) {
    __shared__ float W1s[FIN * F1];
    __shared__ float xs[4 * FIN];
    int tid = threadIdx.x;
    for (int i = tid; i < FIN * F1; i += 256) W1s[i] = W1[i];
    int row0 = blockIdx.x * 4;
    int nrows = min(4, n - row0);
    if (tid < nrows * FIN) xs[tid] = x[(size_t)row0 * FIN + tid];
    __syncthreads();
    int rl = tid >> 6;
    int f  = tid & 63;
    if (rl < nrows) {
        float acc = 0.0f;
        #pragma unroll
        for (int k = 0; k < FIN; k++) acc += xs[rl * FIN + k] * W1s[k * F1 + f];
        int row = row0 + rl;
        g1[(size_t)row * F1 + f] = __float2half(acc * dinv[row]);
    }
}

// ---------- fused: layer-1 gather (fp16 rows) + ReLU + layer-2 GEMM (64->2) ----------
__global__ void k_gather1(const int* __restrict__ rp, const int2* __restrict__ csr,
                          const __half* __restrict__ g1,
                          const float* __restrict__ dinv, const float* __restrict__ b1,
                          const float* __restrict__ W2, float* __restrict__ g2, int n) {
    int wid = (int)((blockIdx.x * (long long)blockDim.x + threadIdx.x) >> 6);
    int f = threadIdx.x & 63;
    if (wid >= n) return;
    int start = rp[wid], end = rp[wid + 1];
    float acc = 0.0f;
    int e = start;
    for (; e + 4 <= end; e += 4) {
        int2 r0 = csr[e], r1 = csr[e+1], r2 = csr[e+2], r3 = csr[e+3];
        float a0 = __half2float(g1[(size_t)r0.x * F1 + f]);
        float a1 = __half2float(g1[(size_t)r1.x * F1 + f]);
        float a2 = __half2float(g1[(size_t)r2.x * F1 + f]);
        float a3 = __half2float(g1[(size_t)r3.x * F1 + f]);
        acc += __int_as_float(r0.y) * a0;
        acc += __int_as_float(r1.y) * a1;
        acc += __int_as_float(r2.y) * a2;
        acc += __int_as_float(r3.y) * a3;
    }
    for (; e < end; e++) {
        int2 r = csr[e];
        acc += __int_as_float(r.y) * __half2float(g1[(size_t)r.x * F1 + f]);
    }
    float dv = dinv[wid];
    float h = dv * (acc + __half2float(g1[(size_t)wid * F1 + f])) + b1[f]; // self-loop w=1
    h = h > 0.0f ? h : 0.0f;
    float2 w2v = ((const float2*)W2)[f];
    float z0 = h * w2v.x, z1 = h * w2v.y;
    #pragma unroll
    for (int off = 32; off > 0; off >>= 1) {
        z0 += __shfl_xor(z0, off, 64);
        z1 += __shfl_xor(z1, off, 64);
    }
    if (f == 0) {
        g2[(size_t)wid * 2 + 0] = dv * z0;
        g2[(size_t)wid * 2 + 1] = dv * z1;
    }
}

// ---------- fused: layer-2 gather + bias + log_softmax ----------
__global__ void k_gather2(const int* __restrict__ rp, const int2* __restrict__ csr,
                          const float* __restrict__ g2,
                          const float* __restrict__ dinv, const float* __restrict__ b2,
                          float* __restrict__ out, int n) {
    int wid = (int)((blockIdx.x * (long long)blockDim.x + threadIdx.x) >> 6);
    int lane = threadIdx.x & 63;
    if (wid >= n) return;
    int start = rp[wid], end = rp[wid + 1];
    float a0 = 0.0f, a1 = 0.0f;
    for (int e = start + lane; e < end; e += 64) {
        int2 r = csr[e];
        float w = __int_as_float(r.y);
        float2 gv = ((const float2*)g2)[r.x];
        a0 += w * gv.x; a1 += w * gv.y;
    }
    #pragma unroll
    for (int off = 32; off > 0; off >>= 1) {
        a0 += __shfl_xor(a0, off, 64);
        a1 += __shfl_xor(a1, off, 64);
    }
    if (lane == 0) {
        float dv = dinv[wid];
        float2 sv = ((const float2*)g2)[wid];        // self-loop
        float z0 = dv * (a0 + sv.x) + b2[0];
        float z1 = dv * (a1 + sv.y) + b2[1];
        float m = fmaxf(z0, z1);
        float lse = m + logf(expf(z0 - m) + expf(z1 - m));
        ((float2*)out)[wid] = make_float2(z0 - lse, z1 - lse);
    }
}

extern "C" void kernel_launch(void* const* d_in, const int* in_sizes, int n_in,
                              void* d_out, int out_size, void* d_ws, size_t ws_size,
                              hipStream_t stream) {
    const float* x  = (const float*)d_in[0];
    const int*   ei = (const int*)d_in[1];    // [2, E]: src row then dst row
    const float* ew = (const float*)d_in[2];
    const float* W1 = (const float*)d_in[3];
    const float* b1 = (const float*)d_in[4];
    const float* W2 = (const float*)d_in[5];
    const float* b2 = (const float*)d_in[6];
    float* out = (float*)d_out;

    int n = in_sizes[0] / FIN;
    int E = in_sizes[2];
    const int* src = ei;
    const int* dst = ei + E;
    int NB = (n + BSZ - 1) / BSZ;             // 391 for n=100000 (<= 512 for k_scan_buck)
    int NCHUNK = (E + CHUNK - 1) / CHUNK;     // 196 for E=3.2M (<= 256 for k_scan_row)
    int M = NB * NCHUNK;

    // workspace carve-out, 16B-aligned
    char* ws = (char*)d_ws;
    size_t off = 0;
    auto alloc = [&](size_t bytes) -> void* {
        void* p = ws + off;
        off += (bytes + 15) & ~(size_t)15;
        return p;
    };
    int*    cmat    = (int*)   alloc((size_t)M * 4);      // 306 KB placement matrix
    int*    rsum    = (int*)   alloc((size_t)NB * 4);
    int*    bbase   = (int*)   alloc((size_t)NB * 4);
    int*    boff    = (int*)   alloc((size_t)(NB + 1) * 4);
    int*    row_ptr = (int*)   alloc((size_t)(n + 1) * 4);
    float*  dinv    = (float*) alloc((size_t)n * 4);
    int2*   recs_a  = (int2*)  alloc((size_t)E * 8);      // 25.6 MB (bucket order)
    int2*   recs_b  = (int2*)  alloc((size_t)E * 8);      // 25.6 MB (node order)
    __half* g1      = (__half*)alloc((size_t)n * F1 * 2); // 12.8 MB
    float*  g2      = (float*) alloc((size_t)n * 2 * 4);

    k_hist     <<<NCHUNK, 256, 0, stream>>>(dst, cmat, E, NB, NCHUNK);
    k_scan_row <<<NB, 256, 0, stream>>>(cmat, rsum, NCHUNK);
    k_scan_buck<<<1, 512, 0, stream>>>(rsum, bbase, boff, NB, E);
    k_place    <<<NCHUNK, 256, 0, stream>>>(src, dst, ew, cmat, bbase, recs_a, E, NB, NCHUNK);
    k_sort     <<<NB, BSZ, 0, stream>>>(boff, recs_a, recs_b, row_ptr, dinv, n);
    k_gemm1    <<<(n + 3) / 4, 256, 0, stream>>>(x, W1, dinv, g1, n);
    k_gather1  <<<(n + 3) / 4, 256, 0, stream>>>(row_ptr, recs_b, g1, dinv, b1, W2, g2, n);
    k_gather2  <<<(n + 3) / 4, 256, 0, stream>>>(row_ptr, recs_b, g2, dinv, b2, out, n);
}

// Round 8
// 395.476 us; speedup vs baseline: 4.4796x; 1.0361x over previous
//
#include <hip/hip_runtime.h>
#include <hip/hip_fp16.h>
#include <math.h>

#define FIN 35
#define F1  64
#define BSZ 256          // nodes per coarse bucket
#define MAXNB 1024       // max buckets supported by k_hist/k_place LDS (n <= 262144)
#define CHUNK 16384      // edges per partition block => NCHUNK <= 256 for E <= 4.19M
#define SORTK 12         // records per thread held in registers in k_sort (cap 12*1024)

// ---------- phase 1: per-chunk histogram of coarse buckets ----------
__global__ void k_hist(const int* __restrict__ dst, int* __restrict__ cmat,
                       int E, int NB, int NCHUNK) {
    __shared__ int h[MAXNB];
    int c = blockIdx.x, t = threadIdx.x;
    for (int i = t; i < NB; i += 256) h[i] = 0;
    __syncthreads();
    int e0 = c * CHUNK, e1 = min(e0 + CHUNK, E);
    for (int e = e0 + t; e < e1; e += 256) atomicAdd(&h[dst[e] >> 8], 1);
    __syncthreads();
    for (int i = t; i < NB; i += 256) cmat[(size_t)i * NCHUNK + c] = h[i];  // b-major
}

// ---------- phase 2a: row-local exclusive scan (one block per bucket row) ----------
// requires NCHUNK <= 256
__global__ void k_scan_row(int* __restrict__ cmat, int* __restrict__ rsum, int NCHUNK) {
    __shared__ int s[256];
    int b = blockIdx.x, t = threadIdx.x;
    int v = (t < NCHUNK) ? cmat[(size_t)b * NCHUNK + t] : 0;
    s[t] = v;
    __syncthreads();
    #pragma unroll
    for (int off = 1; off < 256; off <<= 1) {
        int tv = (t >= off) ? s[t - off] : 0;
        __syncthreads();
        s[t] += tv;
        __syncthreads();
    }
    if (t < NCHUNK) cmat[(size_t)b * NCHUNK + t] = s[t] - v;   // row-local exclusive
    if (t == 255) rsum[b] = s[255];                            // row total
}

// ---------- phase 2b: exclusive scan of row totals -> bucket bases + boff ----------
// requires NB <= 512
__global__ void k_scan_buck(const int* __restrict__ rsum, int* __restrict__ bbase,
                            int* __restrict__ boff, int NB, int E) {
    __shared__ int s[512];
    int t = threadIdx.x;
    int v = (t < NB) ? rsum[t] : 0;
    s[t] = v;
    __syncthreads();
    #pragma unroll
    for (int off = 1; off < 512; off <<= 1) {
        int tv = (t >= off) ? s[t - off] : 0;
        __syncthreads();
        s[t] += tv;
        __syncthreads();
    }
    if (t < NB) {
        int excl = s[t] - v;
        bbase[t] = excl;
        boff[t] = excl;
    }
    if (t == 0) boff[NB] = E;
}

// ---------- phase 3: placement — disjoint per-(block,bucket) windows, zero device atomics ----------
__global__ void k_place(const int* __restrict__ src, const int* __restrict__ dst,
                        const float* __restrict__ ew, const int* __restrict__ cmat,
                        const int* __restrict__ bbase,
                        int2* __restrict__ recs, int E, int NB, int NCHUNK) {
    __shared__ int base[MAXNB];
    __shared__ int cur[MAXNB];
    int c = blockIdx.x, t = threadIdx.x;
    for (int i = t; i < NB; i += 256) {
        base[i] = cmat[(size_t)i * NCHUNK + c] + bbase[i];   // fused "+bucket base"
        cur[i] = 0;
    }
    __syncthreads();
    int e0 = c * CHUNK, e1 = min(e0 + CHUNK, E);
    for (int e = e0 + t; e < e1; e += 256) {
        int d = dst[e];
        int b = d >> 8;
        int r = atomicAdd(&cur[b], 1);          // LDS atomic only
        // pack: low 24 bits = src node (n < 2^24), high 8 bits = dst-local index
        recs[base[b] + r] = make_int2(src[e] | ((d & 255) << 24), __float_as_int(ew[e]));
    }
}

// ---------- per-bucket counting sort: records held in REGISTERS (single global read) ----------
// also emits row_ptr + dinv. 1024 threads; SORTK*1024 = 12288 record capacity
// (avg bucket = E/NB ~ 8200); beyond-capacity tail falls back to global re-read.
__global__ __launch_bounds__(1024) void k_sort(
        const int* __restrict__ boff, const int2* __restrict__ recs_in,
        int2* __restrict__ recs_out, int* __restrict__ row_ptr,
        float* __restrict__ dinv, int n) {
    __shared__ int   hcnt[BSZ];   // per-local-node count, then cursor
    __shared__ int   hoff[BSZ];   // scan scratch
    __shared__ float dsum[BSZ];   // weighted degree
    int b = blockIdx.x, t = threadIdx.x;
    if (t < BSZ) { hcnt[t] = 0; dsum[t] = 1.0f; }   // self-loop weight
    __syncthreads();
    int s0 = boff[b], s1 = boff[b + 1];
    int cnt = s1 - s0;
    int nm = min(cnt, SORTK * 1024);
    // coalesced load into registers: thread t takes records t, t+1024, ...
    int2 r[SORTK];
    int nr = 0;
    for (int i = t; i < nm; i += 1024) r[nr++] = recs_in[s0 + i];
    // histogram + weighted degree from registers
    for (int j = 0; j < nr; j++) {
        int dl = ((unsigned)r[j].x) >> 24;
        atomicAdd(&hcnt[dl], 1);
        atomicAdd(&dsum[dl], __int_as_float(r[j].y));
    }
    // overflow tail (not expected at these sizes)
    for (int i = SORTK * 1024 + t; i < cnt; i += 1024) {
        int2 rec = recs_in[s0 + i];
        int dl = ((unsigned)rec.x) >> 24;
        atomicAdd(&hcnt[dl], 1);
        atomicAdd(&dsum[dl], __int_as_float(rec.y));
    }
    __syncthreads();
    // exclusive scan of 256 counts (first 256 threads work; all hit barriers)
    int v = 0;
    if (t < BSZ) { v = hcnt[t]; hoff[t] = v; }
    __syncthreads();
    #pragma unroll
    for (int off = 1; off < BSZ; off <<= 1) {
        int tv = 0;
        if (t < BSZ && t >= off) tv = hoff[t - off];
        __syncthreads();
        if (t < BSZ) hoff[t] += tv;
        __syncthreads();
    }
    if (t < BSZ) {
        int excl = hoff[t] - v;
        int node = b * BSZ + t;
        if (node < n) {
            row_ptr[node] = s0 + excl;
            dinv[node] = rsqrtf(dsum[t]);
            if (node == n - 1) row_ptr[n] = s1;
        }
        hcnt[t] = excl;           // reuse as local cursor
    }
    __syncthreads();
    // scatter from registers (positions via LDS atomics; window is L2-resident)
    for (int j = 0; j < nr; j++) {
        int dl = ((unsigned)r[j].x) >> 24;
        int pos = atomicAdd(&hcnt[dl], 1);
        recs_out[s0 + pos] = make_int2(r[j].x & 0xFFFFFF, r[j].y);  // clean src
    }
    for (int i = SORTK * 1024 + t; i < cnt; i += 1024) {
        int2 rec = recs_in[s0 + i];
        int dl = ((unsigned)rec.x) >> 24;
        int pos = atomicAdd(&hcnt[dl], 1);
        recs_out[s0 + pos] = make_int2(rec.x & 0xFFFFFF, rec.y);
    }
}

// ---------- layer 1 GEMM: g1[row,f] = fp16( dinv[row] * sum_k x[row,k]*W1[k,f] ) ----------
__global__ void k_gemm1(const float* __restrict__ x, const float* __restrict__ W1,
                        const float* __restrict__ dinv, __half* __restrict__ g1, int n) {
    __shared__ float W1s[FIN * F1];
    __shared__ float xs[4 * FIN];
    int tid = threadIdx.x;
    for (int i = tid; i < FIN * F1; i += 256) W1s[i] = W1[i];
    int row0 = blockIdx.x * 4;
    int nrows = min(4, n - row0);
    if (tid < nrows * FIN) xs[tid] = x[(size_t)row0 * FIN + tid];
    __syncthreads();
    int rl = tid >> 6;
    int f  = tid & 63;
    if (rl < nrows) {
        float acc = 0.0f;
        #pragma unroll
        for (int k = 0; k < FIN; k++) acc += xs[rl * FIN + k] * W1s[k * F1 + f];
        int row = row0 + rl;
        g1[(size_t)row * F1 + f] = __float2half(acc * dinv[row]);
    }
}

// ---------- fused: layer-1 gather (fp16 rows, 8-way MLP) + ReLU + layer-2 GEMM ----------
__global__ void k_gather1(const int* __restrict__ rp, const int2* __restrict__ csr,
                          const __half* __restrict__ g1,
                          const float* __restrict__ dinv, const float* __restrict__ b1,
                          const float* __restrict__ W2, float* __restrict__ g2, int n) {
    int wid = (int)((blockIdx.x * (long long)blockDim.x + threadIdx.x) >> 6);
    int f = threadIdx.x & 63;
    if (wid >= n) return;
    int start = rp[wid], end = rp[wid + 1];
    float acc = 0.0f;
    int e = start;
    for (; e + 8 <= end; e += 8) {             // 8 row-gathers in flight
        int2 r0 = csr[e],   r1 = csr[e+1], r2 = csr[e+2], r3 = csr[e+3];
        int2 r4 = csr[e+4], r5 = csr[e+5], r6 = csr[e+6], r7 = csr[e+7];
        float a0 = __half2float(g1[(size_t)r0.x * F1 + f]);
        float a1 = __half2float(g1[(size_t)r1.x * F1 + f]);
        float a2 = __half2float(g1[(size_t)r2.x * F1 + f]);
        float a3 = __half2float(g1[(size_t)r3.x * F1 + f]);
        float a4 = __half2float(g1[(size_t)r4.x * F1 + f]);
        float a5 = __half2float(g1[(size_t)r5.x * F1 + f]);
        float a6 = __half2float(g1[(size_t)r6.x * F1 + f]);
        float a7 = __half2float(g1[(size_t)r7.x * F1 + f]);
        acc += __int_as_float(r0.y) * a0; acc += __int_as_float(r1.y) * a1;
        acc += __int_as_float(r2.y) * a2; acc += __int_as_float(r3.y) * a3;
        acc += __int_as_float(r4.y) * a4; acc += __int_as_float(r5.y) * a5;
        acc += __int_as_float(r6.y) * a6; acc += __int_as_float(r7.y) * a7;
    }
    for (; e + 4 <= end; e += 4) {
        int2 r0 = csr[e], r1 = csr[e+1], r2 = csr[e+2], r3 = csr[e+3];
        float a0 = __half2float(g1[(size_t)r0.x * F1 + f]);
        float a1 = __half2float(g1[(size_t)r1.x * F1 + f]);
        float a2 = __half2float(g1[(size_t)r2.x * F1 + f]);
        float a3 = __half2float(g1[(size_t)r3.x * F1 + f]);
        acc += __int_as_float(r0.y) * a0; acc += __int_as_float(r1.y) * a1;
        acc += __int_as_float(r2.y) * a2; acc += __int_as_float(r3.y) * a3;
    }
    for (; e < end; e++) {
        int2 r = csr[e];
        acc += __int_as_float(r.y) * __half2float(g1[(size_t)r.x * F1 + f]);
    }
    float dv = dinv[wid];
    float h = dv * (acc + __half2float(g1[(size_t)wid * F1 + f])) + b1[f]; // self-loop w=1
    h = h > 0.0f ? h : 0.0f;
    float2 w2v = ((const float2*)W2)[f];
    float z0 = h * w2v.x, z1 = h * w2v.y;
    #pragma unroll
    for (int off = 32; off > 0; off >>= 1) {
        z0 += __shfl_xor(z0, off, 64);
        z1 += __shfl_xor(z1, off, 64);
    }
    if (f == 0) {
        g2[(size_t)wid * 2 + 0] = dv * z0;
        g2[(size_t)wid * 2 + 1] = dv * z1;
    }
}

// ---------- fused: layer-2 gather (4-way MLP) + bias + log_softmax ----------
__global__ void k_gather2(const int* __restrict__ rp, const int2* __restrict__ csr,
                          const float* __restrict__ g2,
                          const float* __restrict__ dinv, const float* __restrict__ b2,
                          float* __restrict__ out, int n) {
    int wid = (int)((blockIdx.x * (long long)blockDim.x + threadIdx.x) >> 6);
    int lane = threadIdx.x & 63;
    if (wid >= n) return;
    int start = rp[wid], end = rp[wid + 1];
    float a0 = 0.0f, a1 = 0.0f;
    int e = start + lane;
    for (; e + 192 < end; e += 256) {          // 4 gathers in flight
        int2 q0 = csr[e], q1 = csr[e + 64], q2 = csr[e + 128], q3 = csr[e + 192];
        float2 v0 = ((const float2*)g2)[q0.x];
        float2 v1 = ((const float2*)g2)[q1.x];
        float2 v2 = ((const float2*)g2)[q2.x];
        float2 v3 = ((const float2*)g2)[q3.x];
        a0 += __int_as_float(q0.y) * v0.x; a1 += __int_as_float(q0.y) * v0.y;
        a0 += __int_as_float(q1.y) * v1.x; a1 += __int_as_float(q1.y) * v1.y;
        a0 += __int_as_float(q2.y) * v2.x; a1 += __int_as_float(q2.y) * v2.y;
        a0 += __int_as_float(q3.y) * v3.x; a1 += __int_as_float(q3.y) * v3.y;
    }
    for (; e < end; e += 64) {
        int2 r = csr[e];
        float w = __int_as_float(r.y);
        float2 gv = ((const float2*)g2)[r.x];
        a0 += w * gv.x; a1 += w * gv.y;
    }
    #pragma unroll
    for (int off = 32; off > 0; off >>= 1) {
        a0 += __shfl_xor(a0, off, 64);
        a1 += __shfl_xor(a1, off, 64);
    }
    if (lane == 0) {
        float dv = dinv[wid];
        float2 sv = ((const float2*)g2)[wid];        // self-loop
        float z0 = dv * (a0 + sv.x) + b2[0];
        float z1 = dv * (a1 + sv.y) + b2[1];
        float m = fmaxf(z0, z1);
        float lse = m + logf(expf(z0 - m) + expf(z1 - m));
        ((float2*)out)[wid] = make_float2(z0 - lse, z1 - lse);
    }
}

extern "C" void kernel_launch(void* const* d_in, const int* in_sizes, int n_in,
                              void* d_out, int out_size, void* d_ws, size_t ws_size,
                              hipStream_t stream) {
    const float* x  = (const float*)d_in[0];
    const int*   ei = (const int*)d_in[1];    // [2, E]: src row then dst row
    const float* ew = (const float*)d_in[2];
    const float* W1 = (const float*)d_in[3];
    const float* b1 = (const float*)d_in[4];
    const float* W2 = (const float*)d_in[5];
    const float* b2 = (const float*)d_in[6];
    float* out = (float*)d_out;

    int n = in_sizes[0] / FIN;
    int E = in_sizes[2];
    const int* src = ei;
    const int* dst = ei + E;
    int NB = (n + BSZ - 1) / BSZ;             // 391 for n=100000 (<= 512 for k_scan_buck)
    int NCHUNK = (E + CHUNK - 1) / CHUNK;     // 196 for E=3.2M (<= 256 for k_scan_row)
    int M = NB * NCHUNK;

    // workspace carve-out, 16B-aligned
    char* ws = (char*)d_ws;
    size_t off = 0;
    auto alloc = [&](size_t bytes) -> void* {
        void* p = ws + off;
        off += (bytes + 15) & ~(size_t)15;
        return p;
    };
    int*    cmat    = (int*)   alloc((size_t)M * 4);      // 306 KB placement matrix
    int*    rsum    = (int*)   alloc((size_t)NB * 4);
    int*    bbase   = (int*)   alloc((size_t)NB * 4);
    int*    boff    = (int*)   alloc((size_t)(NB + 1) * 4);
    int*    row_ptr = (int*)   alloc((size_t)(n + 1) * 4);
    float*  dinv    = (float*) alloc((size_t)n * 4);
    int2*   recs_a  = (int2*)  alloc((size_t)E * 8);      // 25.6 MB (bucket order)
    int2*   recs_b  = (int2*)  alloc((size_t)E * 8);      // 25.6 MB (node order)
    __half* g1      = (__half*)alloc((size_t)n * F1 * 2); // 12.8 MB
    float*  g2      = (float*) alloc((size_t)n * 2 * 4);

    k_hist     <<<NCHUNK, 256, 0, stream>>>(dst, cmat, E, NB, NCHUNK);
    k_scan_row <<<NB, 256, 0, stream>>>(cmat, rsum, NCHUNK);
    k_scan_buck<<<1, 512, 0, stream>>>(rsum, bbase, boff, NB, E);
    k_place    <<<NCHUNK, 256, 0, stream>>>(src, dst, ew, cmat, bbase, recs_a, E, NB, NCHUNK);
    k_sort     <<<NB, 1024, 0, stream>>>(boff, recs_a, recs_b, row_ptr, dinv, n);
    k_gemm1    <<<(n + 3) / 4, 256, 0, stream>>>(x, W1, dinv, g1, n);
    k_gather1  <<<(n + 3) / 4, 256, 0, stream>>>(row_ptr, recs_b, g1, dinv, b1, W2, g2, n);
    k_gather2  <<<(n + 3) / 4, 256, 0, stream>>>(row_ptr, recs_b, g2, dinv, b2, out, n);
}